// Round 5
// baseline (63.153 us; speedup 1.0000x reference)
//
#include <hip/hip_runtime.h>

#define E10 10

// ============ K1: fused column-sum + base + emb1 ============
// grid (32 jt, 8 b) x 512 thr. Block: 32-col stripe, all 1024 rows.
__global__ __launch_bounds__(512) void k_wsumbase(
    const float* __restrict__ W, const float* __restrict__ feat,
    const float* __restrict__ eww, const float* __restrict__ ewb,
    const float* __restrict__ selw, const float* __restrict__ selb,
    const float* __restrict__ nbww, const float* __restrict__ nbwb,
    const float* __restrict__ nbpb,
    float* __restrict__ base, float* __restrict__ emb1)
{
    __shared__ float smf[32 * 330];   // [rg][col*10+e], row stride 330 (bank-safe)
    __shared__ float sred[320];
    const int t = threadIdx.x;
    const int jt = blockIdx.x, b = blockIdx.y;
    const int cp = t & 15;   // col pair
    const int rg = t >> 4;   // 0..31, 32 rows each
    const int j0 = jt * 32 + cp * 2;

    float cw[E10], cb[E10];
#pragma unroll
    for (int e = 0; e < E10; e++) { cw[e] = eww[e]; cb[e] = ewb[e]; }
    float a0[E10], a1[E10];
#pragma unroll
    for (int e = 0; e < E10; e++) { a0[e] = 0.f; a1[e] = 0.f; }

    const float* Wp = W + (((size_t)(b * 1024 + rg * 32)) << 10) + j0;
#pragma unroll
    for (int s = 0; s < 4; s++) {
        float2 w8[8];
#pragma unroll
        for (int r = 0; r < 8; r++)
            w8[r] = *(const float2*)(Wp + ((size_t)(s * 8 + r) << 10));
#pragma unroll
        for (int r = 0; r < 8; r++) {
#pragma unroll
            for (int e = 0; e < E10; e++) {
                a0[e] += fmaxf(w8[r].x * cw[e] + cb[e], 0.f);
                a1[e] += fmaxf(w8[r].y * cw[e] + cb[e], 0.f);
            }
        }
    }
#pragma unroll
    for (int e = 0; e < E10; e++) {
        smf[rg * 330 + cp * 20 + e]      = a0[e];
        smf[rg * 330 + cp * 20 + 10 + e] = a1[e];
    }
    __syncthreads();
    if (t < 320) {
        float s = 0.f;
#pragma unroll
        for (int r = 0; r < 32; r++) s += smf[r * 330 + t];
        sred[t] = s;
    }
    __syncthreads();
    if (t < 32) {
        float S[E10];
#pragma unroll
        for (int e = 0; e < E10; e++) S[e] = sred[t * 10 + e];
        const int node = b * 1024 + jt * 32 + t;
        const float f = feat[node];
#pragma unroll
        for (int o = 0; o < E10; o++) {
            float bv = nbwb[o];
#pragma unroll
            for (int e = 0; e < E10; e++) bv += S[e] * nbww[o * E10 + e];
            bv += f * selw[o] + selb[o];
            base[(size_t)node * E10 + o] = bv;
            emb1[(size_t)node * E10 + o] = fmaxf(bv + nbpb[o], 0.f);
        }
    }
}

// ============ K2/K3: embOut = relu(base + nbp(A @ embIn)); K3 fuses readout ====
// grid (32 rc, 8 b) x 512 thr. Wave = 4 rows; all 64 lanes share j-space:
// per k-step 5 ds_read_b128 feed 4 rows x 2 j x 10 e = 80 FMA.
template<int FINAL>
__global__ __launch_bounds__(512) void k_iter(
    const float* __restrict__ A,
    const float* __restrict__ embIn,
    const float* __restrict__ base,
    const float* __restrict__ nbpw, const float* __restrict__ nbpb,
    float* __restrict__ embOut,
    float* __restrict__ out,
    float* __restrict__ psum, unsigned* __restrict__ cnt,
    const float* __restrict__ qallw, const float* __restrict__ qallb,
    const float* __restrict__ qredw, const float* __restrict__ qredb,
    const float* __restrict__ qactw, const float* __restrict__ qactb)
{
    __shared__ __align__(16) float2 l2[5 * 1024];   // [e2][j], 40 KB
    const int t = threadIdx.x;
    const int rc = blockIdx.x, b = blockIdx.y;
    const int lane = t & 63, wv = t >> 6;
    const int lg = lane >> 4, ll = lane & 15;

    if (!FINAL && rc == 0) {          // init for the FINAL kernel's election
        if (t == 0) cnt[b] = 0u;
        if (t < E10) psum[b * E10 + t] = 0.f;
    }

    const float2* src = (const float2*)(embIn + (size_t)b * 10240);
    for (int idx = t; idx < 5120; idx += 512) {
        const int j = idx / 5, e2 = idx - j * 5;
        l2[e2 * 1024 + j] = src[idx];
    }

    const int o = (ll < E10) ? ll : 0;
    float nw[E10];
    const float pb = nbpb[o];
#pragma unroll
    for (int e = 0; e < E10; e++) nw[e] = nbpw[o * E10 + e];

    float K2 = 0.f, c2 = 0.f;
    if (FINAL) {
#pragma unroll
        for (int oo = 0; oo < E10; oo++) {
            K2 += qredw[E10 + oo] * qactw[oo * E10 + o];
            c2 += qredw[E10 + oo] * qactb[oo];
        }
        c2 += qredb[0];
        if (ll >= E10) K2 = 0.f;
    }
    __syncthreads();

    const int row0 = rc * 32 + wv * 4;
    const float* Ab = A + (((size_t)(b * 1024 + row0)) << 10);

    float acc[4][E10];
#pragma unroll
    for (int r = 0; r < 4; r++)
#pragma unroll
        for (int e = 0; e < E10; e++) acc[r][e] = 0.f;

    const float4* L4 = (const float4*)l2;

    float2 cur[4], nxt[4];
#pragma unroll
    for (int r = 0; r < 4; r++)
        cur[r] = *(const float2*)(Ab + ((size_t)r << 10) + lane * 2);
#pragma unroll
    for (int k = 0; k < 8; k++) {
        if (k < 7) {
#pragma unroll
            for (int r = 0; r < 4; r++)
                nxt[r] = *(const float2*)(Ab + ((size_t)r << 10) + lane * 2 + (k + 1) * 128);
        }
        const int q0 = lane + k * 64;
        const float4 p0 = L4[q0];
        const float4 p1 = L4[512 + q0];
        const float4 p2 = L4[1024 + q0];
        const float4 p3 = L4[1536 + q0];
        const float4 p4 = L4[2048 + q0];
#pragma unroll
        for (int r = 0; r < 4; r++) {
            const float2 a = cur[r];
            acc[r][0] += a.x * p0.x + a.y * p0.z;
            acc[r][1] += a.x * p0.y + a.y * p0.w;
            acc[r][2] += a.x * p1.x + a.y * p1.z;
            acc[r][3] += a.x * p1.y + a.y * p1.w;
            acc[r][4] += a.x * p2.x + a.y * p2.z;
            acc[r][5] += a.x * p2.y + a.y * p2.w;
            acc[r][6] += a.x * p3.x + a.y * p3.z;
            acc[r][7] += a.x * p3.y + a.y * p3.w;
            acc[r][8] += a.x * p4.x + a.y * p4.z;
            acc[r][9] += a.x * p4.y + a.y * p4.w;
        }
        if (k < 7) {
#pragma unroll
            for (int r = 0; r < 4; r++) cur[r] = nxt[r];
        }
    }

#pragma unroll
    for (int r = 0; r < 4; r++)
#pragma unroll
        for (int e = 0; e < E10; e++) {
            float v = acc[r][e];
            v += __shfl_xor(v, 32);
            v += __shfl_xor(v, 16);
            v += __shfl_xor(v, 8);
            v += __shfl_xor(v, 4);
            v += __shfl_xor(v, 2);
            v += __shfl_xor(v, 1);
            acc[r][e] = v;
        }

    // group lg handles row row0+lg (static-index select, no scratch)
    float te[E10];
#pragma unroll
    for (int e = 0; e < E10; e++)
        te[e] = (lg == 0) ? acc[0][e] : (lg == 1) ? acc[1][e]
              : (lg == 2) ? acc[2][e] : acc[3][e];

    float p = pb;
#pragma unroll
    for (int e = 0; e < E10; e++) p += te[e] * nw[e];

    const int row = row0 + lg;
    const size_t off = ((size_t)(b * 1024 + row)) * E10 + o;
    float v = fmaxf(base[off] + p, 0.f);
    if (ll >= E10) v = 0.f;

    if (!FINAL) {
        if (ll < E10) embOut[off] = v;
    } else {
        if (ll < E10) out[8192 + off] = v;               // emb output
        float pd = v * K2;                                // per-node q part
        pd += __shfl_xor(pd, 8);
        pd += __shfl_xor(pd, 4);
        pd += __shfl_xor(pd, 2);
        pd += __shfl_xor(pd, 1);
        if (ll == 0) out[b * 1024 + row] = c2 + pd;       // sdot added by elected
        float vs = v;                                     // per-e sums over 4 rows
        vs += __shfl_xor(vs, 16);
        vs += __shfl_xor(vs, 32);
        if (lane < E10) atomicAdd(psum + b * E10 + lane, vs);

        __syncthreads();                                  // drain block stores
        __shared__ unsigned eflag;
        __shared__ float s_sdot;
        if (t == 0) {
            __threadfence();                              // release (L2 wb)
            const unsigned old = atomicAdd(cnt + b, 1u);
            eflag = (old == 31u) ? 1u : 0u;
        }
        __syncthreads();
        if (eflag) {
            if (t == 0) {
                __threadfence();                          // acquire (cache inv)
                float sd = 0.f;
#pragma unroll
                for (int oo = 0; oo < E10; oo++) {
                    float se = qallb[oo];
#pragma unroll
                    for (int e = 0; e < E10; e++)
                        se += psum[b * E10 + e] * qallw[oo * E10 + e];
                    sd += se * qredw[oo];
                }
                s_sdot = sd;
            }
            __syncthreads();
            const float sd = s_sdot;
            out[b * 1024 + t]       += sd;
            out[b * 1024 + 512 + t] += sd;
        }
    }
}

extern "C" void kernel_launch(void* const* d_in, const int* in_sizes, int n_in,
                              void* d_out, int out_size, void* d_ws, size_t ws_size,
                              hipStream_t stream) {
    (void)in_sizes; (void)n_in; (void)out_size; (void)ws_size;
    const float* features  = (const float*)d_in[0];
    const float* weights   = (const float*)d_in[1];
    const float* adjacency = (const float*)d_in[2];
    const float* sel_w     = (const float*)d_in[3];
    const float* sel_b     = (const float*)d_in[4];
    const float* nbp_w     = (const float*)d_in[5];
    const float* nbp_b     = (const float*)d_in[6];
    const float* nbw_w     = (const float*)d_in[7];
    const float* nbw_b     = (const float*)d_in[8];
    const float* nbwew_w   = (const float*)d_in[9];
    const float* nbwew_b   = (const float*)d_in[10];
    const float* qred_w    = (const float*)d_in[11];
    const float* qred_b    = (const float*)d_in[12];
    const float* qall_w    = (const float*)d_in[13];
    const float* qall_b    = (const float*)d_in[14];
    const float* qact_w    = (const float*)d_in[15];
    const float* qact_b    = (const float*)d_in[16];
    float* out = (float*)d_out;
    float* ws  = (float*)d_ws;

    float* base = ws;                 // 81920
    float* embA = ws + 81920;         // 81920
    float* embB = embA + 81920;       // 81920
    float* psum = embB + 81920;       // 80
    unsigned* cnt = (unsigned*)(psum + 80);  // 8

    k_wsumbase<<<dim3(32, 8), 512, 0, stream>>>(
        weights, features, nbwew_w, nbwew_b, sel_w, sel_b, nbw_w, nbw_b, nbp_b,
        base, embA);
    k_iter<0><<<dim3(32, 8), 512, 0, stream>>>(
        adjacency, embA, base, nbp_w, nbp_b, embB, out, psum, cnt,
        qall_w, qall_b, qred_w, qred_b, qact_w, qact_b);
    k_iter<1><<<dim3(32, 8), 512, 0, stream>>>(
        adjacency, embB, base, nbp_w, nbp_b, embA, out, psum, cnt,
        qall_w, qall_b, qred_w, qred_b, qact_w, qact_b);
}

// Round 6
// 56.119 us; speedup vs baseline: 1.1253x; 1.1253x over previous
//
#include <hip/hip_runtime.h>

#define E10 10

// ============ K1: column-sum partials (r4-proven, 2048 blocks) ============
// grid (32 jt, 8 ic, 8 b), 256 thr. thread = 8 rows x 2 cols.
__global__ __launch_bounds__(256) void k_wsum(const float* __restrict__ W,
                                              const float* __restrict__ eww,
                                              const float* __restrict__ ewb,
                                              float* __restrict__ Spart,
                                              float* __restrict__ psum,
                                              unsigned* __restrict__ cnt) {
    const int t  = threadIdx.x;
    const int jt = blockIdx.x;   // 0..31
    const int ic = blockIdx.y;   // 0..7
    const int b  = blockIdx.z;   // 0..7
    if (jt == 0 && ic == 0 && b == 0) {       // init for K3's election
        if (t < 8) cnt[t] = 0u;
        else if (t < 88) psum[t - 8] = 0.f;
    }
    const int cp = t & 15;       // col pair
    const int rg = t >> 4;       // row group (16 x 8 rows)
    const int j0 = jt * 32 + cp * 2;
    const int i0 = ic * 128 + rg * 8;

    float cw[E10], cb[E10];
#pragma unroll
    for (int e = 0; e < E10; e++) { cw[e] = eww[e]; cb[e] = ewb[e]; }

    float a0[E10], a1[E10];
#pragma unroll
    for (int e = 0; e < E10; e++) { a0[e] = 0.f; a1[e] = 0.f; }

    const float* Wp = W + ((size_t)(b * 1024 + i0) << 10) + j0;
#pragma unroll
    for (int r = 0; r < 8; r++) {
        const float2 w = *(const float2*)(Wp + ((size_t)r << 10));
#pragma unroll
        for (int e = 0; e < E10; e++) {
            a0[e] += fmaxf(w.x * cw[e] + cb[e], 0.f);
            a1[e] += fmaxf(w.y * cw[e] + cb[e], 0.f);
        }
    }

    __shared__ float smf[16][32][E10];   // 20 KB
#pragma unroll
    for (int e = 0; e < E10; e++) {
        smf[rg][cp * 2][e]     = a0[e];
        smf[rg][cp * 2 + 1][e] = a1[e];
    }
    __syncthreads();
    if (t < 32) {
        float S[E10];
#pragma unroll
        for (int e = 0; e < E10; e++) S[e] = smf[0][t][e];
#pragma unroll
        for (int r = 1; r < 16; r++)
#pragma unroll
            for (int e = 0; e < E10; e++) S[e] += smf[r][t][e];
        float2* Sp = (float2*)(Spart + ((size_t)(ic * 8192 + b * 1024 + jt * 32 + t)) * E10);
#pragma unroll
        for (int q = 0; q < 5; q++) Sp[q] = make_float2(S[2 * q], S[2 * q + 1]);
    }
}

// ============ K2: merge Spart -> base/emb1 (LDS) -> emb2 = relu(base+nbp(A@emb1))
// grid (32 rc, 8 b) x 512 thr.
__global__ __launch_bounds__(512) void k_embiter(
    const float* __restrict__ A,
    const float* __restrict__ Spart,
    const float* __restrict__ feat,
    const float* __restrict__ selw, const float* __restrict__ selb,
    const float* __restrict__ nbww, const float* __restrict__ nbwb,
    const float* __restrict__ nbpw, const float* __restrict__ nbpb,
    float* __restrict__ base, float* __restrict__ emb2)
{
    __shared__ __align__(16) float2 l2[5 * 1024];   // [e2][j], 40 KB
    const int t = threadIdx.x;
    const int rc = blockIdx.x, b = blockIdx.y;
    const int lane = t & 63, wv = t >> 6;
    const int lg = lane >> 4, ll = lane & 15;

    // ---- stage 1: merge 8 Spart chunks for nodes 2t, 2t+1 (regs) ----
    float S[20];
#pragma unroll
    for (int e = 0; e < 20; e++) S[e] = 0.f;
    const float4* Sp4 = (const float4*)(Spart + ((size_t)(b * 1024 + 2 * t)) * E10);
#pragma unroll
    for (int ic = 0; ic < 8; ic++) {
#pragma unroll
        for (int q = 0; q < 5; q++) {
            const float4 v = Sp4[ic * 20480 + q];
            S[4 * q]     += v.x;
            S[4 * q + 1] += v.y;
            S[4 * q + 2] += v.z;
            S[4 * q + 3] += v.w;
        }
    }

    // ---- stage 2: base + emb1 for the 2 nodes; emb1 -> LDS ----
    const float2 f2 = *(const float2*)(feat + b * 1024 + 2 * t);
    float bA[E10], bB[E10];
#pragma unroll
    for (int o = 0; o < E10; o++) {
        float vA = nbwb[o] + f2.x * selw[o] + selb[o];
        float vB = nbwb[o] + f2.y * selw[o] + selb[o];
#pragma unroll
        for (int e = 0; e < E10; e++) {
            vA += S[e] * nbww[o * E10 + e];
            vB += S[10 + e] * nbww[o * E10 + e];
        }
        bA[o] = vA;
        bB[o] = vB;
    }
    float4* L4 = (float4*)l2;
#pragma unroll
    for (int e2 = 0; e2 < 5; e2++) {
        L4[e2 * 512 + t] = make_float4(
            fmaxf(bA[2 * e2] + nbpb[2 * e2], 0.f),
            fmaxf(bA[2 * e2 + 1] + nbpb[2 * e2 + 1], 0.f),
            fmaxf(bB[2 * e2] + nbpb[2 * e2], 0.f),
            fmaxf(bB[2 * e2 + 1] + nbpb[2 * e2 + 1], 0.f));
    }
    // write base for this block's own 32 rows only
    if ((t >> 4) == rc) {
        float4* bp = (float4*)(base + ((size_t)(b * 1024 + 2 * t)) * E10);
        bp[0] = make_float4(bA[0], bA[1], bA[2], bA[3]);
        bp[1] = make_float4(bA[4], bA[5], bA[6], bA[7]);
        bp[2] = make_float4(bA[8], bA[9], bB[0], bB[1]);
        bp[3] = make_float4(bB[2], bB[3], bB[4], bB[5]);
        bp[4] = make_float4(bB[6], bB[7], bB[8], bB[9]);
    }

    const int o = (ll < E10) ? ll : 0;
    float nw[E10];
    const float pb = nbpb[o];
#pragma unroll
    for (int e = 0; e < E10; e++) nw[e] = nbpw[o * E10 + e];
    __syncthreads();

    // ---- stage 3: matmul (r5-proven core) ----
    const int row0 = rc * 32 + wv * 4;
    const float* Ab = A + (((size_t)(b * 1024 + row0)) << 10);

    float acc[4][E10];
#pragma unroll
    for (int r = 0; r < 4; r++)
#pragma unroll
        for (int e = 0; e < E10; e++) acc[r][e] = 0.f;

    const float4* L4c = (const float4*)l2;
    float2 cur[4], nxt[4];
#pragma unroll
    for (int r = 0; r < 4; r++)
        cur[r] = *(const float2*)(Ab + ((size_t)r << 10) + lane * 2);
#pragma unroll
    for (int k = 0; k < 8; k++) {
        if (k < 7) {
#pragma unroll
            for (int r = 0; r < 4; r++)
                nxt[r] = *(const float2*)(Ab + ((size_t)r << 10) + lane * 2 + (k + 1) * 128);
        }
        const int q0 = lane + k * 64;
        const float4 p0 = L4c[q0];
        const float4 p1 = L4c[512 + q0];
        const float4 p2 = L4c[1024 + q0];
        const float4 p3 = L4c[1536 + q0];
        const float4 p4 = L4c[2048 + q0];
#pragma unroll
        for (int r = 0; r < 4; r++) {
            const float2 a = cur[r];
            acc[r][0] += a.x * p0.x + a.y * p0.z;
            acc[r][1] += a.x * p0.y + a.y * p0.w;
            acc[r][2] += a.x * p1.x + a.y * p1.z;
            acc[r][3] += a.x * p1.y + a.y * p1.w;
            acc[r][4] += a.x * p2.x + a.y * p2.z;
            acc[r][5] += a.x * p2.y + a.y * p2.w;
            acc[r][6] += a.x * p3.x + a.y * p3.z;
            acc[r][7] += a.x * p3.y + a.y * p3.w;
            acc[r][8] += a.x * p4.x + a.y * p4.z;
            acc[r][9] += a.x * p4.y + a.y * p4.w;
        }
        if (k < 7) {
#pragma unroll
            for (int r = 0; r < 4; r++) cur[r] = nxt[r];
        }
    }

#pragma unroll
    for (int r = 0; r < 4; r++)
#pragma unroll
        for (int e = 0; e < E10; e++) {
            float v = acc[r][e];
            v += __shfl_xor(v, 32);
            v += __shfl_xor(v, 16);
            v += __shfl_xor(v, 8);
            v += __shfl_xor(v, 4);
            v += __shfl_xor(v, 2);
            v += __shfl_xor(v, 1);
            acc[r][e] = v;
        }

    float te[E10];
#pragma unroll
    for (int e = 0; e < E10; e++)
        te[e] = (lg == 0) ? acc[0][e] : (lg == 1) ? acc[1][e]
              : (lg == 2) ? acc[2][e] : acc[3][e];

    float p = pb;
#pragma unroll
    for (int e = 0; e < E10; e++) p += te[e] * nw[e];

    const int row = row0 + lg;
    const size_t off = ((size_t)(b * 1024 + row)) * E10 + o;
    if (ll < E10) emb2[off] = fmaxf(base[off] + p, 0.f);
}

// ============ K3: emb3 = relu(base+nbp(A@emb2)) + full readout (election) ====
__global__ __launch_bounds__(512) void k_last(
    const float* __restrict__ A,
    const float* __restrict__ embIn,
    const float* __restrict__ base,
    const float* __restrict__ nbpw, const float* __restrict__ nbpb,
    float* __restrict__ out,
    float* __restrict__ psum, unsigned* __restrict__ cnt,
    const float* __restrict__ qallw, const float* __restrict__ qallb,
    const float* __restrict__ qredw, const float* __restrict__ qredb,
    const float* __restrict__ qactw, const float* __restrict__ qactb)
{
    __shared__ __align__(16) float2 l2[5 * 1024];   // 40 KB
    const int t = threadIdx.x;
    const int rc = blockIdx.x, b = blockIdx.y;
    const int lane = t & 63, wv = t >> 6;
    const int lg = lane >> 4, ll = lane & 15;

    const float2* src = (const float2*)(embIn + (size_t)b * 10240);
    for (int idx = t; idx < 5120; idx += 512) {
        const int j = idx / 5, e2 = idx - j * 5;
        l2[e2 * 1024 + j] = src[idx];
    }

    const int o = (ll < E10) ? ll : 0;
    float nw[E10];
    const float pb = nbpb[o];
#pragma unroll
    for (int e = 0; e < E10; e++) nw[e] = nbpw[o * E10 + e];

    float K2c = 0.f, c2 = 0.f;
#pragma unroll
    for (int oo = 0; oo < E10; oo++) {
        K2c += qredw[E10 + oo] * qactw[oo * E10 + o];
        c2  += qredw[E10 + oo] * qactb[oo];
    }
    c2 += qredb[0];
    if (ll >= E10) K2c = 0.f;
    __syncthreads();

    const int row0 = rc * 32 + wv * 4;
    const float* Ab = A + (((size_t)(b * 1024 + row0)) << 10);

    float acc[4][E10];
#pragma unroll
    for (int r = 0; r < 4; r++)
#pragma unroll
        for (int e = 0; e < E10; e++) acc[r][e] = 0.f;

    const float4* L4 = (const float4*)l2;
    float2 cur[4], nxt[4];
#pragma unroll
    for (int r = 0; r < 4; r++)
        cur[r] = *(const float2*)(Ab + ((size_t)r << 10) + lane * 2);
#pragma unroll
    for (int k = 0; k < 8; k++) {
        if (k < 7) {
#pragma unroll
            for (int r = 0; r < 4; r++)
                nxt[r] = *(const float2*)(Ab + ((size_t)r << 10) + lane * 2 + (k + 1) * 128);
        }
        const int q0 = lane + k * 64;
        const float4 p0 = L4[q0];
        const float4 p1 = L4[512 + q0];
        const float4 p2 = L4[1024 + q0];
        const float4 p3 = L4[1536 + q0];
        const float4 p4 = L4[2048 + q0];
#pragma unroll
        for (int r = 0; r < 4; r++) {
            const float2 a = cur[r];
            acc[r][0] += a.x * p0.x + a.y * p0.z;
            acc[r][1] += a.x * p0.y + a.y * p0.w;
            acc[r][2] += a.x * p1.x + a.y * p1.z;
            acc[r][3] += a.x * p1.y + a.y * p1.w;
            acc[r][4] += a.x * p2.x + a.y * p2.z;
            acc[r][5] += a.x * p2.y + a.y * p2.w;
            acc[r][6] += a.x * p3.x + a.y * p3.z;
            acc[r][7] += a.x * p3.y + a.y * p3.w;
            acc[r][8] += a.x * p4.x + a.y * p4.z;
            acc[r][9] += a.x * p4.y + a.y * p4.w;
        }
        if (k < 7) {
#pragma unroll
            for (int r = 0; r < 4; r++) cur[r] = nxt[r];
        }
    }

#pragma unroll
    for (int r = 0; r < 4; r++)
#pragma unroll
        for (int e = 0; e < E10; e++) {
            float v = acc[r][e];
            v += __shfl_xor(v, 32);
            v += __shfl_xor(v, 16);
            v += __shfl_xor(v, 8);
            v += __shfl_xor(v, 4);
            v += __shfl_xor(v, 2);
            v += __shfl_xor(v, 1);
            acc[r][e] = v;
        }

    float te[E10];
#pragma unroll
    for (int e = 0; e < E10; e++)
        te[e] = (lg == 0) ? acc[0][e] : (lg == 1) ? acc[1][e]
              : (lg == 2) ? acc[2][e] : acc[3][e];

    float p = pb;
#pragma unroll
    for (int e = 0; e < E10; e++) p += te[e] * nw[e];

    const int row = row0 + lg;
    const size_t off = ((size_t)(b * 1024 + row)) * E10 + o;
    float v = fmaxf(base[off] + p, 0.f);
    if (ll >= E10) v = 0.f;

    if (ll < E10) out[8192 + off] = v;                // emb output
    float pd = v * K2c;                               // per-node q part
    pd += __shfl_xor(pd, 8);
    pd += __shfl_xor(pd, 4);
    pd += __shfl_xor(pd, 2);
    pd += __shfl_xor(pd, 1);
    if (ll == 0) out[b * 1024 + row] = c2 + pd;       // sdot added by elected
    float vs = v;                                     // per-e sums over 4 rows
    vs += __shfl_xor(vs, 16);
    vs += __shfl_xor(vs, 32);

    // block-level pre-reduce, then 10 global atomics per block
    __shared__ float sps[E10];
    if (t < E10) sps[t] = 0.f;
    __syncthreads();
    if (lane < E10) atomicAdd(&sps[lane], vs);
    __syncthreads();
    if (t < E10) atomicAdd(psum + b * E10 + t, sps[t]);
    __syncthreads();                                  // drain block's stores

    __shared__ unsigned eflag;
    __shared__ float s_sdot;
    if (t == 0) {
        __threadfence();                              // release (L2 wb)
        const unsigned old = atomicAdd(cnt + b, 1u);
        eflag = (old == 31u) ? 1u : 0u;
    }
    __syncthreads();
    if (eflag) {
        if (t == 0) {
            __threadfence();                          // acquire (cache inv)
            float sd = 0.f;
#pragma unroll
            for (int oo = 0; oo < E10; oo++) {
                float se = qallb[oo];
#pragma unroll
                for (int e = 0; e < E10; e++)
                    se += psum[b * E10 + e] * qallw[oo * E10 + e];
                sd += se * qredw[oo];
            }
            s_sdot = sd;
        }
        __syncthreads();
        const float sd = s_sdot;
        out[b * 1024 + t]       += sd;
        out[b * 1024 + 512 + t] += sd;
    }
}

extern "C" void kernel_launch(void* const* d_in, const int* in_sizes, int n_in,
                              void* d_out, int out_size, void* d_ws, size_t ws_size,
                              hipStream_t stream) {
    (void)in_sizes; (void)n_in; (void)out_size; (void)ws_size;
    const float* features  = (const float*)d_in[0];
    const float* weights   = (const float*)d_in[1];
    const float* adjacency = (const float*)d_in[2];
    const float* sel_w     = (const float*)d_in[3];
    const float* sel_b     = (const float*)d_in[4];
    const float* nbp_w     = (const float*)d_in[5];
    const float* nbp_b     = (const float*)d_in[6];
    const float* nbw_w     = (const float*)d_in[7];
    const float* nbw_b     = (const float*)d_in[8];
    const float* nbwew_w   = (const float*)d_in[9];
    const float* nbwew_b   = (const float*)d_in[10];
    const float* qred_w    = (const float*)d_in[11];
    const float* qred_b    = (const float*)d_in[12];
    const float* qall_w    = (const float*)d_in[13];
    const float* qall_b    = (const float*)d_in[14];
    const float* qact_w    = (const float*)d_in[15];
    const float* qact_b    = (const float*)d_in[16];
    float* out = (float*)d_out;
    float* ws  = (float*)d_ws;

    float* Spart = ws;                       // 8*8192*10 = 655360
    float* base  = ws + 655360;              // 81920
    float* emb2  = base + 81920;             // 81920
    float* psum  = emb2 + 81920;             // 80
    unsigned* cnt = (unsigned*)(psum + 80);  // 8

    k_wsum<<<dim3(32, 8, 8), 256, 0, stream>>>(weights, nbwew_w, nbwew_b, Spart,
                                               psum, cnt);
    k_embiter<<<dim3(32, 8), 512, 0, stream>>>(
        adjacency, Spart, features, sel_w, sel_b, nbw_w, nbw_b, nbp_w, nbp_b,
        base, emb2);
    k_last<<<dim3(32, 8), 512, 0, stream>>>(
        adjacency, emb2, base, nbp_w, nbp_b, out, psum, cnt,
        qall_w, qall_b, qred_w, qred_b, qact_w, qact_b);
}